// Round 4
// baseline (230.401 us; speedup 1.0000x reference)
//
#include <hip/hip_runtime.h>

#define BB 32
#define TT 128
#define PP 512
#define DD 300
#define KT 10      // K chunks of 32 (KP = 320 = 300 data + bias slot + zeros)
#define AT 256     // A tiles (4096/16)
#define BT 448     // B tiles (7168/16)
#define CTS 114    // LDS C-tile row stride in floats
#define NEG -1e30f

typedef _Float16 half8 __attribute__((ext_vector_type(8)));
typedef float floatx4 __attribute__((ext_vector_type(4)));

__device__ __forceinline__ void async_load16(const void* g, void* l) {
    __builtin_amdgcn_global_load_lds(
        (const __attribute__((address_space(1))) void*)g,
        (__attribute__((address_space(3))) void*)l, 16, 0, 0);
}

__device__ __forceinline__ floatx4 mfma16(half8 a, half8 b, floatx4 c) {
    return __builtin_amdgcn_mfma_f32_16x16x32_f16(a, b, c, 0, 0, 0);
}

// ---------------------------------------------------------------------------
// Pack into MFMA-fragment-blocked layout + error-free f16 Dekker split
// (x = hi + lo*2^-12, lo stored *4096). UNCHANGED from R0.
// ---------------------------------------------------------------------------
__global__ __launch_bounds__(256) void pack_kernel(
    const int* __restrict__ tokens, const float* __restrict__ emb,
    const float* __restrict__ diags, const float* __restrict__ bias,
    _Float16* __restrict__ AhP, _Float16* __restrict__ AlP,
    _Float16* __restrict__ BhP, _Float16* __restrict__ BlP)
{
    const int idx = blockIdx.x * 256 + threadIdx.x;
    if (idx >= (AT + BT) * KT * 64) return;
    const int chunk = idx >> 6;
    const int ln = idx & 63;

    const float* src;
    float kslot;
    _Float16 *dh, *dl;
    int kt;
    if (chunk < AT * KT) {
        const int mt = chunk / KT; kt = chunk - mt * KT;
        const int m = mt * 16 + (ln & 15);
        src = emb + (size_t)tokens[m] * DD;
        kslot = 1.0f;
        dh = AhP + (size_t)chunk * 512 + ln * 8;
        dl = AlP + (size_t)chunk * 512 + ln * 8;
    } else {
        const int c2 = chunk - AT * KT;
        const int nt = c2 / KT; kt = c2 - nt * KT;
        const int n = nt * 16 + (ln & 15);       // srow = n directly
        src = diags + (size_t)n * DD;
        kslot = bias[n];
        dh = BhP + (size_t)c2 * 512 + ln * 8;
        dl = BlP + (size_t)c2 * 512 + ln * 8;
    }

    const int k0 = kt * 32 + (ln >> 4) * 8;
    float v[8];
    if (k0 + 8 <= DD) {
        float4 a = *(const float4*)(src + k0);
        float4 b = *(const float4*)(src + k0 + 4);
        v[0] = a.x; v[1] = a.y; v[2] = a.z; v[3] = a.w;
        v[4] = b.x; v[5] = b.y; v[6] = b.z; v[7] = b.w;
    } else {
        #pragma unroll
        for (int i = 0; i < 8; ++i) {
            const int k = k0 + i;
            v[i] = (k < DD) ? src[k] : (k == DD ? kslot : 0.f);
        }
    }
    half8 h, l;
    #pragma unroll
    for (int i = 0; i < 8; ++i) {
        h[i] = (_Float16)v[i];
        l[i] = (_Float16)((v[i] - (float)h[i]) * 4096.f);
    }
    *(half8*)dh = h;
    *(half8*)dl = l;
}

// ---------------------------------------------------------------------------
// FUSED GEMM + max-sum scan.
// R3 post-mortem: tail (8 lanes, 2-deep prefetch) exposed ~120cy LDS latency
// per step and the register ceiling (112 AGPR + 112 VGPR = 224/wave -> 8
// waves/CU) means no extra blocks can hide it. R4 changes:
//  * dead-wave unswitch: wave w owns rows t in [32w,32w+32); if 32w >= dl
//    the scan never reads those rows -> wave runs a stage-only K-loop
//    (identical barrier count), skipping loadA + all MFMAs + dump. Live
//    path is VERBATIM R3 (no per-kt guards -> no R2-style spills).
//  * tail: 4-deep static-slot prefetch (structure of the proven 19us scan
//    kernel) so ds_read latency is fully hidden; s_setprio(1) around the
//    serial tail so it wins issue arbitration vs co-resident GEMM waves.
// Live-row accumulators and scan arithmetic are bit-identical to R3.
// ---------------------------------------------------------------------------
__global__ __launch_bounds__(256, 2) void gemm_scan_kernel(
    const _Float16* __restrict__ AhP, const _Float16* __restrict__ AlP,
    const _Float16* __restrict__ BhP, const _Float16* __restrict__ BlP,
    const float* __restrict__ epsilons,
    const int* __restrict__ doc_lens,
    float* __restrict__ scores)
{
    // union: Bs (28672B) alive during K-loop; Ct (58368B) alive after.
    __shared__ __align__(16) unsigned char smem[128 * CTS * 4];
    typedef _Float16 BsT[2][7][512];              // [h/l][ntile][frag]
    BsT* Bs = reinterpret_cast<BsT*>(smem);       // Bs[dbuf][h/l][nt][frag]
    float (*Ct)[CTS] = reinterpret_cast<float(*)[CTS]>(smem);

    const int tid = threadIdx.x;
    const int w = tid >> 6, ln = tid & 63;
    const int bx = blockIdx.x;                    // 0..63: patterns 8bx..8bx+7
    const int b  = blockIdx.y;                    // batch element; rows = t

    const int dl = doc_lens[b];                   // in [64, 128]
    const bool live = (32 * w < dl);              // wave's rows below dl?

    floatx4 acc0[2][7], acc1[2][7];
    #pragma unroll
    for (int i = 0; i < 2; ++i)
        #pragma unroll
        for (int j = 0; j < 7; ++j) {
            acc0[i][j] = (floatx4){0.f, 0.f, 0.f, 0.f};
            acc1[i][j] = (floatx4){0.f, 0.f, 0.f, 0.f};
        }

    half8 ah[2][2], al[2][2];

    auto loadA = [&](int kt, int pb) {
        #pragma unroll
        for (int i = 0; i < 2; ++i) {
            const size_t ch = ((size_t)(b * 8 + 2 * w + i) * KT + kt) * 512 + ln * 8;
            ah[pb][i] = *(const half8*)(AhP + ch);
            al[pb][i] = *(const half8*)(AlP + ch);
        }
    };
    // 14 1KB chunks per kt (7 ntiles x h/l) spread over 4 waves.
    auto stageB = [&](int kt, int buf) {
        #pragma unroll
        for (int s = 0; s < 4; ++s) {
            const int cidx = w + 4 * s;
            if (cidx < 14) {
                const int nt = cidx >> 1, hl = cidx & 1;
                const size_t ch = ((size_t)(7 * bx + nt) * KT + kt) * 512 + ln * 8;
                async_load16((hl ? BlP : BhP) + ch, &Bs[buf][hl][nt][0]);
            }
        }
    };

    stageB(0, 0);
    if (live) loadA(0, 0);
    __syncthreads();

    if (live) {
        // ---- verbatim R3 K-loop ----
        #pragma unroll
        for (int kt = 0; kt < KT; ++kt) {
            const int cb = kt & 1, nb = cb ^ 1;
            if (kt + 1 < KT) {
                loadA(kt + 1, nb);
                stageB(kt + 1, nb);
            }
            #pragma unroll
            for (int j = 0; j < 7; ++j) {
                const half8 bh = *(const half8*)&Bs[cb][0][j][ln * 8];
                const half8 bl = *(const half8*)&Bs[cb][1][j][ln * 8];
                #pragma unroll
                for (int i = 0; i < 2; ++i) {
                    acc0[i][j] = mfma16(ah[cb][i], bh, acc0[i][j]);
                    acc1[i][j] = mfma16(ah[cb][i], bl, acc1[i][j]);
                    acc1[i][j] = mfma16(al[cb][i], bh, acc1[i][j]);
                }
            }
            __syncthreads();
        }
    } else {
        // ---- dead wave: stage-only loop, identical barrier count ----
        #pragma unroll
        for (int kt = 0; kt < KT; ++kt) {
            const int nb = (kt & 1) ^ 1;
            if (kt + 1 < KT) stageB(kt + 1, nb);
            __syncthreads();
        }
    }

    // dump fragments to LDS tile. C/D layout: col=lane&15, row=(lane>>4)*4+r.
    if (live) {
        #pragma unroll
        for (int j = 0; j < 7; ++j) {
            const int col = j * 16 + (ln & 15);
            #pragma unroll
            for (int i = 0; i < 2; ++i) {
                const int rb = (2 * w + i) * 16 + (ln >> 4) * 4;
                #pragma unroll
                for (int r = 0; r < 4; ++r)
                    Ct[rb + r][col] = acc0[i][j][r] + acc1[i][j][r] * (1.0f / 4096.0f);
            }
        }
    }
    __syncthreads();
    if (w != 0) return;          // waves 1..3 done; no barriers after this
    if (ln >= 8) return;         // wave 0 lanes 0..7: one pattern each

    // ---- scan tail: pattern p = 8*bx + ln, cols 14*ln .. +13 of Ct ----
    const int p = bx * 8 + ln;
    const int c0 = ln * 14;
    const bool end5 = (p < 256);

    float e[6];
    #pragma unroll
    for (int i = 0; i < 6; ++i) e[i] = epsilons[p * 6 + i];

    float h0 = 0.f, h1 = NEG, h2 = NEG, h3 = NEG, h4 = NEG, h5 = NEG, h6 = NEG;
    float sc = NEG;

    // 4-deep static-slot prefetch (rule #20: slot indices compile-time only).
    float2 buf[4][7];
    auto load = [&](int slot, int t) {
        const float* row = &Ct[t][c0];           // 8B-aligned (CTS even)
        #pragma unroll
        for (int i = 0; i < 7; ++i) buf[slot][i] = *(const float2*)(row + 2 * i);
    };
    auto step = [&](int slot) {
        const float2* v = buf[slot];
        float ae0 = h0;
        float ae1 = fmaxf(h1, h0 + e[0]);
        float ae2 = fmaxf(h2, h1 + e[1]);
        float ae3 = fmaxf(h3, h2 + e[2]);
        float ae4 = fmaxf(h4, h3 + e[3]);
        float ae5 = fmaxf(h5, h4 + e[4]);
        float ae6 = fmaxf(h6, h5 + e[5]);
        h0 = fmaxf(0.f,          ae0 + v[0].x);
        h1 = fmaxf(ae0 + v[3].y, ae1 + v[0].y);
        h2 = fmaxf(ae1 + v[4].x, ae2 + v[1].x);
        h3 = fmaxf(ae2 + v[4].y, ae3 + v[1].y);
        h4 = fmaxf(ae3 + v[5].x, ae4 + v[2].x);
        h5 = fmaxf(ae4 + v[5].y, ae5 + v[2].y);
        h6 = fmaxf(ae5 + v[6].x, ae6 + v[3].x);
        sc = fmaxf(sc, end5 ? h5 : h6);          // every executed step t < dl
    };

    __builtin_amdgcn_s_setprio(1);
    #pragma unroll
    for (int j = 0; j < 4; ++j) load(j, j);

    int tb = 0;
    for (; tb + 4 <= dl; tb += 4) {
        #pragma unroll
        for (int j = 0; j < 4; ++j) {
            step(j);
            const int t = tb + j + 4;
            load(j, t > 127 ? 127 : t);          // clamp; clamped slots are
        }                                        // consumed only if t < dl
    }
    const int rem = dl - tb;                     // 0..3, uniform over lanes
    #pragma unroll
    for (int j = 0; j < 3; ++j)
        if (j < rem) step(j);
    __builtin_amdgcn_s_setprio(0);

    scores[p * BB + b] = sc;
}

// ---------------------------------------------------------------------------
// BatchNorm (batch stats) + sign(relu) + final linear. One block. UNCHANGED.
// ---------------------------------------------------------------------------
__global__ __launch_bounds__(512) void finalize_kernel(
    const float* __restrict__ scores,
    const float* __restrict__ bn_w,
    const float* __restrict__ bn_b,
    const float* __restrict__ fw,
    const float* __restrict__ fb,
    float* __restrict__ out)
{
    __shared__ float acc[64];
    const int p = threadIdx.x;
    if (p < 64) acc[p] = 0.f;
    __syncthreads();

    float x[32];
    const float4* sp = (const float4*)(scores + p * 32);
    #pragma unroll
    for (int i = 0; i < 8; ++i) ((float4*)x)[i] = sp[i];

    float mean = 0.f;
    #pragma unroll
    for (int i = 0; i < 32; ++i) mean += x[i];
    mean *= (1.f / 32.f);
    float var = 0.f;
    #pragma unroll
    for (int i = 0; i < 32; ++i) { const float d = x[i] - mean; var = fmaf(d, d, var); }
    var *= (1.f / 32.f);

    const float scale = (1.f / sqrtf(var + 1e-5f)) * bn_w[p];
    const float shift = bn_b[p];
    const float w0 = fw[p], w1 = fw[PP + p];

    for (int b = 0; b < 32; ++b) {
        const float v = (x[b] - mean) * scale + shift;
        const bool bin = v > 0.f;
        float v0 = bin ? w0 : 0.f;
        float v1 = bin ? w1 : 0.f;
        #pragma unroll
        for (int o = 32; o; o >>= 1) {
            v0 += __shfl_xor(v0, o);
            v1 += __shfl_xor(v1, o);
        }
        if ((threadIdx.x & 63) == 0) {
            atomicAdd(&acc[b * 2 + 0], v0);
            atomicAdd(&acc[b * 2 + 1], v1);
        }
    }
    __syncthreads();
    if (p < 64) out[p] = acc[p] + fb[p & 1];
}

// ---------------------------------------------------------------------------
extern "C" void kernel_launch(void* const* d_in, const int* in_sizes, int n_in,
                              void* d_out, int out_size, void* d_ws, size_t ws_size,
                              hipStream_t stream) {
    const int*   tokens   = (const int*)d_in[0];
    const int*   doc_lens = (const int*)d_in[1];
    const float* emb      = (const float*)d_in[2];
    const float* diags    = (const float*)d_in[3];
    const float* bias     = (const float*)d_in[4];
    const float* eps      = (const float*)d_in[5];
    const float* bnw      = (const float*)d_in[6];
    const float* bnb      = (const float*)d_in[7];
    const float* fw       = (const float*)d_in[8];
    const float* fb       = (const float*)d_in[9];
    float* out = (float*)d_out;

    float* scores = (float*)d_ws;                    // [512][32]
    _Float16* AhP = (_Float16*)(scores + PP * BB);   // frag-blocked packs
    _Float16* AlP = AhP + (size_t)AT * KT * 512;
    _Float16* BhP = AlP + (size_t)AT * KT * 512;
    _Float16* BlP = BhP + (size_t)BT * KT * 512;

    pack_kernel<<<(AT + BT) * KT * 64 / 256, 256, 0, stream>>>(
        tokens, emb, diags, bias, AhP, AlP, BhP, BlP);
    gemm_scan_kernel<<<dim3(64, BB), 256, 0, stream>>>(
        AhP, AlP, BhP, BlP, eps, doc_lens, scores);
    finalize_kernel<<<1, 512, 0, stream>>>(scores, bnw, bnb, fw, fb, out);
}